// Round 2
// baseline (326.302 us; speedup 1.0000x reference)
//
#include <hip/hip_runtime.h>

#define HW 64
#define NPIX 4096
#define NB 128
#define NA 10
#define HCH 150
#define VS 68      // LDS row stride (64 + 2 ring + pad)
#define VROWS 66

// workspace float offsets
#define R_OFF 0
#define R_SZ (NB * NPIX)        // 524288 floats
#define K5_OFF (R_SZ)           // 50 floats: K5[2][5][5]
#define C_OFF (K5_OFF + 50)     // 1
#define M_OFF (C_OFF + 1)       // 162: M[9][2][9]
#define BD_OFF (M_OFF + 162)    // 9
#define N_PRE 222               // 50 + 1 + 162 + 9

// ---------------------------------------------------------------------------
// Kernel 0: fold the 2->150->1 conv pair into composed 5x5 kernel + border
// correction kernels. One block (1 wave) per output element; channel loop
// split across the 64 lanes + shuffle reduction.
// ---------------------------------------------------------------------------
__global__ __launch_bounds__(64) void precompute_kernels(
        const float* __restrict__ Wh,   // [150][2][9]
        const float* __restrict__ bh,   // [150]
        const float* __restrict__ Wr,   // [150][9]
        float* __restrict__ ws) {
    int o = blockIdx.x;      // 0..221
    int lane = threadIdx.x;  // 0..63
    float s = 0.f;
    if (o < 50) {
        // K5[ci][u][v] = sum_ch sum_{ky,kx} Wr[ch][ky][kx] * Wh[ch][ci][u-ky][v-kx]
        int ci = o / 25, uv = o % 25, u = uv / 5, v = uv % 5;
        for (int ch = lane; ch < HCH; ch += 64) {
            const float* wr = Wr + ch * 9;
            const float* wh = Wh + ch * 18 + ci * 9;
            for (int ky = 0; ky < 3; ++ky) {
                int ey = u - ky; if (ey < 0 || ey > 2) continue;
                for (int kx = 0; kx < 3; ++kx) {
                    int ex = v - kx; if (ex < 0 || ex > 2) continue;
                    s += wr[ky * 3 + kx] * wh[ey * 3 + ex];
                }
            }
        }
    } else if (o == 50) {
        // C = sum_ch bh[ch] * sum_t Wr[ch][t]
        for (int ch = lane; ch < HCH; ch += 64) {
            float wsum = 0.f;
            for (int t = 0; t < 9; ++t) wsum += Wr[ch * 9 + t];
            s += wsum * bh[ch];
        }
    } else if (o < 51 + 162) {
        // M[d][ci][e] = sum_ch Wr[ch][d] * Wh[ch][ci][e]
        int m = o - 51;
        int d = m / 18, rest = m % 18, ci = rest / 9, e = rest % 9;
        for (int ch = lane; ch < HCH; ch += 64)
            s += Wr[ch * 9 + d] * Wh[ch * 18 + ci * 9 + e];
    } else {
        // Bd[d] = sum_ch Wr[ch][d] * bh[ch]
        int d = o - 213;
        for (int ch = lane; ch < HCH; ch += 64)
            s += Wr[ch * 9 + d] * bh[ch];
    }
    #pragma unroll
    for (int off = 32; off > 0; off >>= 1) s += __shfl_down(s, off);
    if (lane == 0) ws[K5_OFF + o] = s;
}

// ---------------------------------------------------------------------------
// Kernel 1: r = composed 5x5 conv on obs (+C), with exact border corrections
// for the second conv's zero padding of r_img. One thread per output pixel.
// ---------------------------------------------------------------------------
__global__ __launch_bounds__(256) void compute_r(
        const float* __restrict__ obs,    // [128][2][64][64]
        const float* __restrict__ wsro,   // K5/C/M/Bd region (ws base)
        float* __restrict__ rg) {         // [128][64][64]
    int idx = blockIdx.x * 256 + threadIdx.x;   // 0 .. 524287
    int b = idx >> 12, p = idx & 4095, y = p >> 6, x = p & 63;
    const float* ob0 = obs + (size_t)b * 2 * NPIX;
    const float* ob1 = ob0 + NPIX;
    const float* K5 = wsro + K5_OFF;
    float acc = wsro[C_OFF];
    #pragma unroll
    for (int u = 0; u < 5; ++u) {
        int gy = y + u - 2;
        if (gy < 0 || gy > 63) continue;
        #pragma unroll
        for (int v = 0; v < 5; ++v) {
            int gx = x + v - 2;
            if (gx < 0 || gx > 63) continue;
            acc += K5[u * 5 + v] * ob0[gy * 64 + gx]
                 + K5[25 + u * 5 + v] * ob1[gy * 64 + gx];
        }
    }
    if (y == 0 || y == 63 || x == 0 || x == 63) {
        const float* M  = wsro + M_OFF;
        const float* Bd = wsro + BD_OFF;
        for (int d = 0; d < 9; ++d) {
            int ny = y + d / 3 - 1, nx = x + d % 3 - 1;
            if (ny >= 0 && ny <= 63 && nx >= 0 && nx <= 63) continue;
            // subtract virtual r_img contribution at out-of-domain (ny,nx)
            float corr = Bd[d];
            for (int e = 0; e < 9; ++e) {
                int oy = ny + e / 3 - 1, ox = nx + e % 3 - 1;
                if (oy < 0 || oy > 63 || ox < 0 || ox > 63) continue;
                corr += M[d * 18 + e]     * ob0[oy * 64 + ox]
                      + M[d * 18 + 9 + e] * ob1[oy * 64 + ox];
            }
            acc -= corr;
        }
    }
    rg[idx] = acc;
}

// ---------------------------------------------------------------------------
// Kernel 2: full value iteration, one block per image, 1024 threads
// (2x2 pixels/thread). qr (r-contribution to q, iteration-invariant) and Wv
// in registers; v double-buffered in LDS with a zero ring -> ONE barrier per
// iteration. r is staged in buffer 0 (only needed for the qr pass), which is
// then recycled as the second v buffer. Final gather + FC done by the thread
// owning the attended pixel (its qr is register-resident).
// ---------------------------------------------------------------------------
__global__ __launch_bounds__(1024, 1) void vi_kernel(
        const float* __restrict__ rg,     // [128][64][64]
        const float* __restrict__ Wi,     // w_i2q [10][9]
        const float* __restrict__ Wvq,    // w_v2q [10][9]
        const float* __restrict__ Wfc,    // [8][10]
        const int* __restrict__ s1, const int* __restrict__ s2,
        const int* __restrict__ kptr,
        float* __restrict__ out) {        // [128][8]
    __shared__ float buf0[VROWS * VS];    // r, then v (even targets)
    __shared__ float buf1[VROWS * VS];    // v (odd targets)
    __shared__ float wil[90];
    __shared__ float wvl[90];
    int tid = threadIdx.x;
    int b = blockIdx.x;

    for (int i = tid; i < VROWS * VS; i += 1024) { buf0[i] = 0.f; buf1[i] = 0.f; }
    if (tid < 90) { wil[tid] = Wi[tid]; wvl[tid] = Wvq[tid]; }
    __syncthreads();

    // stage r into buf0 interior
    const float* rb = rg + (size_t)b * NPIX;
    for (int i = tid; i < NPIX; i += 1024) {
        int y = i >> 6, x = i & 63;
        buf0[(y + 1) * VS + (x + 1)] = rb[i];
    }
    __syncthreads();

    // thread owns a 2-row x 2-col patch
    int tx = tid & 31, ty = tid >> 5;
    int x0 = tx * 2, y0 = ty * 2;

    // Wv into registers (shared across all 4 pixels, all iterations)
    float wv[NA][9];
    #pragma unroll
    for (int a = 0; a < NA; ++a)
        #pragma unroll
        for (int t = 0; t < 9; ++t) wv[a][t] = wvl[a * 9 + t];

    // qr[pixel][action] = conv(r, Wi) at pixel; v0 = max_a qr  -> buf1
    float qr[4][NA];
    {
        float rn[4][4];
        #pragma unroll
        for (int r = 0; r < 4; ++r)
            #pragma unroll
            for (int c = 0; c < 4; ++c)
                rn[r][c] = buf0[(y0 + r) * VS + (x0 + c)];
        #pragma unroll
        for (int py = 0; py < 2; ++py) {
            #pragma unroll
            for (int px = 0; px < 2; ++px) {
                float vmax = -1e30f;
                #pragma unroll
                for (int a = 0; a < NA; ++a) {
                    float acc = 0.f;
                    #pragma unroll
                    for (int ky = 0; ky < 3; ++ky)
                        #pragma unroll
                        for (int kx = 0; kx < 3; ++kx)
                            acc += wil[a * 9 + ky * 3 + kx] * rn[py + ky][px + kx];
                    qr[py * 2 + px][a] = acc;
                    vmax = fmaxf(vmax, acc);
                }
                buf1[(y0 + py + 1) * VS + (x0 + px + 1)] = vmax;
            }
        }
    }
    __syncthreads();
    // buf1 = v_cur; buf0's interior (r values) is dead and gets fully
    // overwritten in iteration 0 before anyone reads it as v. Rings stay 0.

    int K = kptr[0];
    float* cur = buf1;
    float* nxt = buf0;
    for (int it = 0; it < K; ++it) {
        float vn[4][4];
        #pragma unroll
        for (int r = 0; r < 4; ++r)
            #pragma unroll
            for (int c = 0; c < 4; ++c)
                vn[r][c] = cur[(y0 + r) * VS + (x0 + c)];
        #pragma unroll
        for (int py = 0; py < 2; ++py) {
            #pragma unroll
            for (int px = 0; px < 2; ++px) {
                float m = -1e30f;
                #pragma unroll
                for (int a = 0; a < NA; ++a) {
                    float acc = qr[py * 2 + px][a];
                    #pragma unroll
                    for (int ky = 0; ky < 3; ++ky)
                        #pragma unroll
                        for (int kx = 0; kx < 3; ++kx)
                            acc += wv[a][ky * 3 + kx] * vn[py + ky][px + kx];
                    m = fmaxf(m, acc);
                }
                nxt[(y0 + py + 1) * VS + (x0 + px + 1)] = m;
            }
        }
        __syncthreads();   // writes(it) visible before reads(it+1); reads(it)
                           // happened before this barrier so writes(it+1) are safe
        float* t = cur; cur = nxt; nxt = t;
    }

    // final q at attended pixel + FC, by the owning thread (qr in its regs)
    int yy = s1[b], xx = s2[b];
    if (ty == (yy >> 1) && tx == (xx >> 1)) {
        int py = yy & 1, px = xx & 1;
        float q[NA];
        #pragma unroll
        for (int a = 0; a < NA; ++a) {
            float acc = qr[py * 2 + px][a];
            #pragma unroll
            for (int ky = 0; ky < 3; ++ky)
                #pragma unroll
                for (int kx = 0; kx < 3; ++kx)
                    acc += wv[a][ky * 3 + kx] * cur[(yy + ky) * VS + (xx + kx)];
            q[a] = acc;
        }
        for (int n = 0; n < 8; ++n) {
            float o = 0.f;
            for (int a = 0; a < NA; ++a) o += q[a] * Wfc[n * NA + a];
            out[b * 8 + n] = o;
        }
    }
}

// ---------------------------------------------------------------------------
extern "C" void kernel_launch(void* const* d_in, const int* in_sizes, int n_in,
                              void* d_out, int out_size, void* d_ws, size_t ws_size,
                              hipStream_t stream) {
    const int*   s1   = (const int*)d_in[0];
    const int*   s2   = (const int*)d_in[1];
    const float* obs  = (const float*)d_in[2];
    const int*   kptr = (const int*)d_in[3];
    const float* Wh   = (const float*)d_in[4];
    const float* bh   = (const float*)d_in[5];
    const float* Wr   = (const float*)d_in[6];
    const float* Wi   = (const float*)d_in[7];
    const float* Wvq  = (const float*)d_in[8];
    const float* Wfc  = (const float*)d_in[9];
    float* out = (float*)d_out;
    float* ws  = (float*)d_ws;

    precompute_kernels<<<N_PRE, 64, 0, stream>>>(Wh, bh, Wr, ws);
    compute_r<<<2048, 256, 0, stream>>>(obs, ws, ws + R_OFF);
    vi_kernel<<<NB, 1024, 0, stream>>>(ws + R_OFF, Wi, Wvq, Wfc, s1, s2, kptr, out);
}

// Round 3
// 214.924 us; speedup vs baseline: 1.5182x; 1.5182x over previous
//
#include <hip/hip_runtime.h>

#define HW 64
#define NPIX 4096
#define NB 128
#define NA 10
#define HCH 150
#define VS 68      // LDS row stride (64 + 2 ring + pad)
#define VROWS 66

// workspace float offsets
#define R_OFF 0
#define R_SZ (NB * NPIX)        // 524288 floats
#define K5_OFF (R_SZ)           // 50 floats: K5[2][5][5]
#define C_OFF (K5_OFF + 50)     // 1
#define M_OFF (C_OFF + 1)       // 162: M[9][2][9]
#define BD_OFF (M_OFF + 162)    // 9
#define N_PRE 222               // 50 + 1 + 162 + 9

// ---------------------------------------------------------------------------
// Kernel 0: fold the 2->150->1 conv pair into composed 5x5 kernel + border
// correction kernels. One block (1 wave) per output element; channel loop
// split across the 64 lanes + shuffle reduction.
// ---------------------------------------------------------------------------
__global__ __launch_bounds__(64) void precompute_kernels(
        const float* __restrict__ Wh,   // [150][2][9]
        const float* __restrict__ bh,   // [150]
        const float* __restrict__ Wr,   // [150][9]
        float* __restrict__ ws) {
    int o = blockIdx.x;      // 0..221
    int lane = threadIdx.x;  // 0..63
    float s = 0.f;
    if (o < 50) {
        // K5[ci][u][v] = sum_ch sum_{ky,kx} Wr[ch][ky][kx] * Wh[ch][ci][u-ky][v-kx]
        int ci = o / 25, uv = o % 25, u = uv / 5, v = uv % 5;
        for (int ch = lane; ch < HCH; ch += 64) {
            const float* wr = Wr + ch * 9;
            const float* wh = Wh + ch * 18 + ci * 9;
            for (int ky = 0; ky < 3; ++ky) {
                int ey = u - ky; if (ey < 0 || ey > 2) continue;
                for (int kx = 0; kx < 3; ++kx) {
                    int ex = v - kx; if (ex < 0 || ex > 2) continue;
                    s += wr[ky * 3 + kx] * wh[ey * 3 + ex];
                }
            }
        }
    } else if (o == 50) {
        // C = sum_ch bh[ch] * sum_t Wr[ch][t]
        for (int ch = lane; ch < HCH; ch += 64) {
            float wsum = 0.f;
            for (int t = 0; t < 9; ++t) wsum += Wr[ch * 9 + t];
            s += wsum * bh[ch];
        }
    } else if (o < 51 + 162) {
        // M[d][ci][e] = sum_ch Wr[ch][d] * Wh[ch][ci][e]
        int m = o - 51;
        int d = m / 18, rest = m % 18, ci = rest / 9, e = rest % 9;
        for (int ch = lane; ch < HCH; ch += 64)
            s += Wr[ch * 9 + d] * Wh[ch * 18 + ci * 9 + e];
    } else {
        // Bd[d] = sum_ch Wr[ch][d] * bh[ch]
        int d = o - 213;
        for (int ch = lane; ch < HCH; ch += 64)
            s += Wr[ch * 9 + d] * bh[ch];
    }
    #pragma unroll
    for (int off = 32; off > 0; off >>= 1) s += __shfl_down(s, off);
    if (lane == 0) ws[K5_OFF + o] = s;
}

// ---------------------------------------------------------------------------
// Kernel 1: r = composed 5x5 conv on obs (+C), with exact border corrections
// for the second conv's zero padding of r_img. One thread per output pixel.
// ---------------------------------------------------------------------------
__global__ __launch_bounds__(256) void compute_r(
        const float* __restrict__ obs,    // [128][2][64][64]
        const float* __restrict__ wsro,   // K5/C/M/Bd region (ws base)
        float* __restrict__ rg) {         // [128][64][64]
    int idx = blockIdx.x * 256 + threadIdx.x;   // 0 .. 524287
    int b = idx >> 12, p = idx & 4095, y = p >> 6, x = p & 63;
    const float* ob0 = obs + (size_t)b * 2 * NPIX;
    const float* ob1 = ob0 + NPIX;
    const float* K5 = wsro + K5_OFF;
    float acc = wsro[C_OFF];
    #pragma unroll
    for (int u = 0; u < 5; ++u) {
        int gy = y + u - 2;
        if (gy < 0 || gy > 63) continue;
        #pragma unroll
        for (int v = 0; v < 5; ++v) {
            int gx = x + v - 2;
            if (gx < 0 || gx > 63) continue;
            acc += K5[u * 5 + v] * ob0[gy * 64 + gx]
                 + K5[25 + u * 5 + v] * ob1[gy * 64 + gx];
        }
    }
    if (y == 0 || y == 63 || x == 0 || x == 63) {
        const float* M  = wsro + M_OFF;
        const float* Bd = wsro + BD_OFF;
        for (int d = 0; d < 9; ++d) {
            int ny = y + d / 3 - 1, nx = x + d % 3 - 1;
            if (ny >= 0 && ny <= 63 && nx >= 0 && nx <= 63) continue;
            // subtract virtual r_img contribution at out-of-domain (ny,nx)
            float corr = Bd[d];
            for (int e = 0; e < 9; ++e) {
                int oy = ny + e / 3 - 1, ox = nx + e % 3 - 1;
                if (oy < 0 || oy > 63 || ox < 0 || ox > 63) continue;
                corr += M[d * 18 + e]     * ob0[oy * 64 + ox]
                      + M[d * 18 + 9 + e] * ob1[oy * 64 + ox];
            }
            acc -= corr;
        }
    }
    rg[idx] = acc;
}

// ---------------------------------------------------------------------------
// Kernel 2: full value iteration, one block per image, 512 threads
// (4x2 pixels/thread — the R1 shape that compiled to a healthy VGPR count;
// 1024 threads triggered a 64-VGPR cap + scratch spill).
// qr (r-contribution to q, iteration-invariant) and Wv in registers; v
// double-buffered in LDS with a zero ring -> ONE barrier per iteration.
// r is staged in buf0 (only needed for the qr pass), which is then recycled
// as the second v buffer. Final gather + FC by the attended pixel's owner.
// ---------------------------------------------------------------------------
__global__ __launch_bounds__(512, 2) void vi_kernel(
        const float* __restrict__ rg,     // [128][64][64]
        const float* __restrict__ Wi,     // w_i2q [10][9]
        const float* __restrict__ Wvq,    // w_v2q [10][9]
        const float* __restrict__ Wfc,    // [8][10]
        const int* __restrict__ s1, const int* __restrict__ s2,
        const int* __restrict__ kptr,
        float* __restrict__ out) {        // [128][8]
    __shared__ float buf0[VROWS * VS];    // r, then v buffer
    __shared__ float buf1[VROWS * VS];    // v buffer
    __shared__ float wil[90];
    __shared__ float wvl[90];
    int tid = threadIdx.x;
    int b = blockIdx.x;

    for (int i = tid; i < VROWS * VS; i += 512) { buf0[i] = 0.f; buf1[i] = 0.f; }
    if (tid < 90) { wil[tid] = Wi[tid]; wvl[tid] = Wvq[tid]; }
    __syncthreads();

    // stage r into buf0 interior (float4 loads; rows are 64 floats = 16 float4)
    const float4* rb4 = (const float4*)(rg + (size_t)b * NPIX);
    for (int i = tid; i < NPIX / 4; i += 512) {
        float4 v = rb4[i];
        int p = i * 4, y = p >> 6, x = p & 63;
        float* dst = &buf0[(y + 1) * VS + (x + 1)];
        dst[0] = v.x; dst[1] = v.y; dst[2] = v.z; dst[3] = v.w;
    }
    __syncthreads();

    // thread owns a 4-row x 2-col patch
    int tx = tid & 31, ty = tid >> 5;
    int x0 = tx * 2, y0 = ty * 4;

    // qr[pixel][action] = conv(r, Wi) at pixel; v0 = max_a qr  -> buf1
    float qr[8][NA];
    {
        float wt[NA][9];
        #pragma unroll
        for (int a = 0; a < NA; ++a)
            #pragma unroll
            for (int t = 0; t < 9; ++t) wt[a][t] = wil[a * 9 + t];
        float rn[6][4];
        #pragma unroll
        for (int r = 0; r < 6; ++r)
            #pragma unroll
            for (int c = 0; c < 4; ++c)
                rn[r][c] = buf0[(y0 + r) * VS + (x0 + c)];
        #pragma unroll
        for (int py = 0; py < 4; ++py) {
            #pragma unroll
            for (int px = 0; px < 2; ++px) {
                float vmax = -1e30f;
                #pragma unroll
                for (int a = 0; a < NA; ++a) {
                    float acc = 0.f;
                    #pragma unroll
                    for (int ky = 0; ky < 3; ++ky)
                        #pragma unroll
                        for (int kx = 0; kx < 3; ++kx)
                            acc += wt[a][ky * 3 + kx] * rn[py + ky][px + kx];
                    qr[py * 2 + px][a] = acc;
                    vmax = fmaxf(vmax, acc);
                }
                buf1[(y0 + py + 1) * VS + (x0 + px + 1)] = vmax;
            }
        }
    }

    // Wv into registers (shared across all 8 pixels, all iterations)
    float wv[NA][9];
    #pragma unroll
    for (int a = 0; a < NA; ++a)
        #pragma unroll
        for (int t = 0; t < 9; ++t) wv[a][t] = wvl[a * 9 + t];
    __syncthreads();
    // buf1 = v_cur; buf0's interior (r) is dead — fully overwritten in
    // iteration 0 before anyone reads it as v. Rings of both buffers stay 0.

    int K = kptr[0];
    float* cur = buf1;
    float* nxt = buf0;
    for (int it = 0; it < K; ++it) {
        float vn[6][4];
        #pragma unroll
        for (int r = 0; r < 6; ++r)
            #pragma unroll
            for (int c = 0; c < 4; ++c)
                vn[r][c] = cur[(y0 + r) * VS + (x0 + c)];
        #pragma unroll
        for (int py = 0; py < 4; ++py) {
            #pragma unroll
            for (int px = 0; px < 2; ++px) {
                float m = -1e30f;
                #pragma unroll
                for (int a = 0; a < NA; ++a) {
                    float acc = qr[py * 2 + px][a];
                    #pragma unroll
                    for (int ky = 0; ky < 3; ++ky)
                        #pragma unroll
                        for (int kx = 0; kx < 3; ++kx)
                            acc += wv[a][ky * 3 + kx] * vn[py + ky][px + kx];
                    m = fmaxf(m, acc);
                }
                nxt[(y0 + py + 1) * VS + (x0 + px + 1)] = m;
            }
        }
        __syncthreads();   // writes(it) visible before reads(it+1); reads(it)
                           // completed before this barrier so writes(it+1) are safe
        float* t = cur; cur = nxt; nxt = t;
    }

    // final q at attended pixel + FC, by the owning thread (qr in its regs)
    int yy = s1[b], xx = s2[b];
    if (ty == (yy >> 2) && tx == (xx >> 1)) {
        int py = yy & 3, px = xx & 1;
        float q[NA];
        #pragma unroll
        for (int a = 0; a < NA; ++a) {
            float acc = qr[py * 2 + px][a];
            #pragma unroll
            for (int ky = 0; ky < 3; ++ky)
                #pragma unroll
                for (int kx = 0; kx < 3; ++kx)
                    acc += wv[a][ky * 3 + kx] * cur[(yy + ky) * VS + (xx + kx)];
            q[a] = acc;
        }
        for (int n = 0; n < 8; ++n) {
            float o = 0.f;
            for (int a = 0; a < NA; ++a) o += q[a] * Wfc[n * NA + a];
            out[b * 8 + n] = o;
        }
    }
}

// ---------------------------------------------------------------------------
extern "C" void kernel_launch(void* const* d_in, const int* in_sizes, int n_in,
                              void* d_out, int out_size, void* d_ws, size_t ws_size,
                              hipStream_t stream) {
    const int*   s1   = (const int*)d_in[0];
    const int*   s2   = (const int*)d_in[1];
    const float* obs  = (const float*)d_in[2];
    const int*   kptr = (const int*)d_in[3];
    const float* Wh   = (const float*)d_in[4];
    const float* bh   = (const float*)d_in[5];
    const float* Wr   = (const float*)d_in[6];
    const float* Wi   = (const float*)d_in[7];
    const float* Wvq  = (const float*)d_in[8];
    const float* Wfc  = (const float*)d_in[9];
    float* out = (float*)d_out;
    float* ws  = (float*)d_ws;

    precompute_kernels<<<N_PRE, 64, 0, stream>>>(Wh, bh, Wr, ws);
    compute_r<<<2048, 256, 0, stream>>>(obs, ws, ws + R_OFF);
    vi_kernel<<<NB, 512, 0, stream>>>(ws + R_OFF, Wi, Wvq, Wfc, s1, s2, kptr, out);
}